// Round 4
// baseline (15100.465 us; speedup 1.0000x reference)
//
#include <hip/hip_runtime.h>
#include <cmath>

#define TT   2048
#define EE   300
#define HH   512
#define G4H  2048     // 4*H
#define NTAG 25
#define NEGV (-10000.0f)
#define POISON 0xFFBADBADu   // NaN payload; real gate values can never equal this

__device__ __forceinline__ float fsig(float x)  { return 1.f / (1.f + __expf(-x)); }
__device__ __forceinline__ float ftanh(float x) { return 1.f - 2.f / (__expf(2.f * x) + 1.f); }
__device__ __forceinline__ uint32_t f2u(float x) { return __float_as_uint(x); }
__device__ __forceinline__ float u2f(uint32_t x) { return __uint_as_float(x); }

// ---------------- poison gates buffer (data-as-sync sentinel) ----------------
__global__ void poison_kernel(uint32_t* __restrict__ p, int n) {
    int i = blockIdx.x * blockDim.x + threadIdx.x;
    for (; i < n; i += gridDim.x * blockDim.x) p[i] = POISON;
}

// ---------------- embedding gather ----------------
__global__ void embed_kernel(const int* __restrict__ sent,
                             const float* __restrict__ emb,
                             float* __restrict__ x) {
    int t = blockIdx.x;
    int row = sent[t];
    const float4* src = (const float4*)(emb + (size_t)row * EE);
    float4* dst = (float4*)(x + (size_t)t * EE);
    for (int i = threadIdx.x; i < EE / 4; i += blockDim.x) dst[i] = src[i];
}

// ---------------- GEMM (generic, bounds-checked): C = A*B^T + b1 (+ b2) ------
#define BM 64
#define BN 64
#define BKK 16
__global__ __launch_bounds__(256)
void gemm_abt(const float* __restrict__ A, int lda,
              const float* __restrict__ B, int ldb,
              const float* __restrict__ bias1,
              const float* __restrict__ bias2,
              float* __restrict__ C, int ldc,
              int M, int N, int K) {
    __shared__ float As[BKK][BM + 4];
    __shared__ float Bs[BKK][BN + 4];
    const int tid = threadIdx.x;
    const int tx = tid & 15, ty = tid >> 4;
    const int bm = blockIdx.x * BM, bn = blockIdx.y * BN;
    float acc[4][4] = {};
    for (int k0 = 0; k0 < K; k0 += BKK) {
        #pragma unroll
        for (int i = 0; i < 4; ++i) {
            int m = (tid >> 4) + i * 16;
            int k = tid & 15;
            float a = 0.f, b = 0.f;
            if (k0 + k < K) {
                if (bm + m < M) a = A[(size_t)(bm + m) * lda + k0 + k];
                if (bn + m < N) b = B[(size_t)(bn + m) * ldb + k0 + k];
            }
            As[k][m] = a;
            Bs[k][m] = b;
        }
        __syncthreads();
        #pragma unroll
        for (int k = 0; k < BKK; ++k) {
            float4 a4 = *(const float4*)&As[k][ty * 4];
            float4 b4 = *(const float4*)&Bs[k][tx * 4];
            acc[0][0] += a4.x * b4.x; acc[0][1] += a4.x * b4.y;
            acc[0][2] += a4.x * b4.z; acc[0][3] += a4.x * b4.w;
            acc[1][0] += a4.y * b4.x; acc[1][1] += a4.y * b4.y;
            acc[1][2] += a4.y * b4.z; acc[1][3] += a4.y * b4.w;
            acc[2][0] += a4.z * b4.x; acc[2][1] += a4.z * b4.y;
            acc[2][2] += a4.z * b4.z; acc[2][3] += a4.z * b4.w;
            acc[3][0] += a4.w * b4.x; acc[3][1] += a4.w * b4.y;
            acc[3][2] += a4.w * b4.z; acc[3][3] += a4.w * b4.w;
        }
        __syncthreads();
    }
    #pragma unroll
    for (int i = 0; i < 4; ++i) {
        int m = bm + ty * 4 + i;
        if (m < M) {
            #pragma unroll
            for (int j = 0; j < 4; ++j) {
                int n = bn + tx * 4 + j;
                if (n < N) {
                    float v = acc[i][j];
                    if (bias1) v += bias1[n];
                    if (bias2) v += bias2[n];
                    C[(size_t)m * ldc + n] = v;
                }
            }
        }
    }
}

// ---------------- big GEMM (128x128 tile, 8x8/thread) ----------------
#define GM 128
#define GN 128
#define GK 16
__global__ __launch_bounds__(256)
void gemm128(const float* __restrict__ A, int lda,
             const float* __restrict__ B, int ldb,
             const float* __restrict__ bias1,
             const float* __restrict__ bias2,
             float* __restrict__ C, int ldc, int K) {
    __shared__ float As[GK][GM + 4];
    __shared__ float Bs[GK][GN + 4];
    const int tid = threadIdx.x;
    const int tx = tid & 15, ty = tid >> 4;
    const int bm = blockIdx.x * GM, bn = blockIdx.y * GN;
    const int lm = tid >> 1, lkq = (tid & 1) * 8;
    float acc[8][8] = {};
    for (int k0 = 0; k0 < K; k0 += GK) {
        float4 a0 = *(const float4*)&A[(size_t)(bm + lm) * lda + k0 + lkq];
        float4 a1 = *(const float4*)&A[(size_t)(bm + lm) * lda + k0 + lkq + 4];
        float4 b0 = *(const float4*)&B[(size_t)(bn + lm) * ldb + k0 + lkq];
        float4 b1 = *(const float4*)&B[(size_t)(bn + lm) * ldb + k0 + lkq + 4];
        As[lkq + 0][lm] = a0.x; As[lkq + 1][lm] = a0.y;
        As[lkq + 2][lm] = a0.z; As[lkq + 3][lm] = a0.w;
        As[lkq + 4][lm] = a1.x; As[lkq + 5][lm] = a1.y;
        As[lkq + 6][lm] = a1.z; As[lkq + 7][lm] = a1.w;
        Bs[lkq + 0][lm] = b0.x; Bs[lkq + 1][lm] = b0.y;
        Bs[lkq + 2][lm] = b0.z; Bs[lkq + 3][lm] = b0.w;
        Bs[lkq + 4][lm] = b1.x; Bs[lkq + 5][lm] = b1.y;
        Bs[lkq + 6][lm] = b1.z; Bs[lkq + 7][lm] = b1.w;
        __syncthreads();
        #pragma unroll
        for (int k = 0; k < GK; ++k) {
            float4 x0 = *(const float4*)&As[k][ty * 8];
            float4 x1 = *(const float4*)&As[k][ty * 8 + 4];
            float4 y0 = *(const float4*)&Bs[k][tx * 8];
            float4 y1 = *(const float4*)&Bs[k][tx * 8 + 4];
            float xa[8] = {x0.x, x0.y, x0.z, x0.w, x1.x, x1.y, x1.z, x1.w};
            float yb[8] = {y0.x, y0.y, y0.z, y0.w, y1.x, y1.y, y1.z, y1.w};
            #pragma unroll
            for (int i = 0; i < 8; ++i)
                #pragma unroll
                for (int j = 0; j < 8; ++j)
                    acc[i][j] += xa[i] * yb[j];
        }
        __syncthreads();
    }
    #pragma unroll
    for (int i = 0; i < 8; ++i) {
        int m = bm + ty * 8 + i;
        float* cr = C + (size_t)m * ldc + bn + tx * 8;
        #pragma unroll
        for (int j = 0; j < 8; ++j) {
            float v = acc[i][j];
            int n = bn + tx * 8 + j;
            if (bias1) v += bias1[n];
            if (bias2) v += bias2[n];
            cr[j] = v;
        }
    }
}

// ------------- persistent dual-direction BiLSTM (gate-publish, r=4 blocking) --
// 32 WGs x 512 threads. WG wg owns fwd units [wg*16,wg*16+16) AND the same bwd
// units. Per iteration: consume fwd gates(s-1), dot fwd(s); consume bwd
// gates(s-1), dot bwd(s) -- each direction's L3 poll hides under the other
// direction's compute. Thread (g=tid>>5, l=tid&31) computes rows 4g..4g+3
// against h chunk floats {4(l+32i)..+3, i=0..3} (reuse 4 -> LDS traffic /4).
__global__ __launch_bounds__(512, 2)
void lstm_kernel(const float* __restrict__ gx,      // [2][T][4H] input proj + biases
                 const float* __restrict__ whh_f,   // [4H][H]
                 const float* __restrict__ whh_b,   // [4H][H]
                 float* __restrict__ gates,         // [2][T][4H] poisoned
                 float* __restrict__ hout)          // [T][2H]
{
    const int tid = threadIdx.x;
    const int wg  = blockIdx.x;          // 0..31
    const int g   = tid >> 5;            // row group 0..15 (4 rows each)
    const int l   = tid & 31;            // reduction lane
    const int gb  = g >> 2;              // gate block of rows 4g..4g+3
    const int growb = gb * HH + wg * 16 + (g & 3) * 4;   // first of 4 consecutive rows

    // weights: 4 rows x 16 floats per dir = 16 float4 per dir
    float4 wf[16], wb[16];
    #pragma unroll
    for (int j = 0; j < 4; ++j) {
        const float4* rf = (const float4*)(whh_f + (size_t)(growb + j) * HH);
        const float4* rb = (const float4*)(whh_b + (size_t)(growb + j) * HH);
        #pragma unroll
        for (int i = 0; i < 4; ++i) {
            wf[j * 4 + i] = rf[l + 32 * i];
            wb[j * 4 + i] = rb[l + 32 * i];
        }
    }
    #pragma unroll
    for (int i = 0; i < 16; ++i) {
        asm volatile("" : "+v"(wf[i].x), "+v"(wf[i].y), "+v"(wf[i].z), "+v"(wf[i].w));
        asm volatile("" : "+v"(wb[i].x), "+v"(wb[i].y), "+v"(wb[i].z), "+v"(wb[i].w));
    }

    __shared__ float hf_s[HH];
    __shared__ float hb_s[HH];

    float cf = 0.f, cb = 0.f;            // replicated cell state of unit `tid`
    uint32_t* gfp = (uint32_t*)gates;
    uint32_t* gbp = (uint32_t*)(gates + (size_t)TT * G4H);
    const float* gxf = gx;
    const float* gxb = gx + (size_t)TT * G4H;

    // gx prefetch pipeline (l==0 lanes), one float4 (4 consecutive rows) per dir
    float4 xfc{}, xfn{}, xff{}, xbc{}, xbn{}, xbf{};
    if (l == 0) {
        xfc = *(const float4*)(gxf + (size_t)0 * G4H + growb);
        xfn = *(const float4*)(gxf + (size_t)1 * G4H + growb);
        xbc = *(const float4*)(gxb + (size_t)(TT - 1) * G4H + growb);
        xbn = *(const float4*)(gxb + (size_t)(TT - 2) * G4H + growb);
    }

    for (int s = 0; s <= TT; ++s) {
        // ================= forward half =================
        float hfv;
        if (s > 0) {
            const uint32_t* p = gfp + (size_t)(s - 1) * G4H + tid;
            uint32_t v0, v1, v2, v3;
            for (;;) {
                v0 = __hip_atomic_load(p,        __ATOMIC_RELAXED, __HIP_MEMORY_SCOPE_AGENT);
                v1 = __hip_atomic_load(p + 512,  __ATOMIC_RELAXED, __HIP_MEMORY_SCOPE_AGENT);
                v2 = __hip_atomic_load(p + 1024, __ATOMIC_RELAXED, __HIP_MEMORY_SCOPE_AGENT);
                v3 = __hip_atomic_load(p + 1536, __ATOMIC_RELAXED, __HIP_MEMORY_SCOPE_AGENT);
                if ((v0 != POISON) & (v1 != POISON) & (v2 != POISON) & (v3 != POISON)) break;
            }
            float gi = fsig(u2f(v0));
            float gf = fsig(u2f(v1));
            float gg = ftanh(u2f(v2));
            float go = fsig(u2f(v3));
            cf = gf * cf + gi * gg;
            hfv = go * ftanh(cf);
            if (wg == 0) hout[(size_t)(s - 1) * (2 * HH) + tid] = hfv;
        } else {
            hfv = 0.f;
        }
        hf_s[tid] = hfv;
        __syncthreads();                               // B1: hf ready (also orders prev bwd dot)

        if (s < TT) {
            float a0 = 0.f, a1 = 0.f, a2 = 0.f, a3 = 0.f;
            const float4* h4 = (const float4*)hf_s;
            #pragma unroll
            for (int i = 0; i < 4; ++i) {
                float4 hv = h4[l + 32 * i];
                a0 += wf[0 + i].x * hv.x + wf[0 + i].y * hv.y + wf[0 + i].z * hv.z + wf[0 + i].w * hv.w;
                a1 += wf[4 + i].x * hv.x + wf[4 + i].y * hv.y + wf[4 + i].z * hv.z + wf[4 + i].w * hv.w;
                a2 += wf[8 + i].x * hv.x + wf[8 + i].y * hv.y + wf[8 + i].z * hv.z + wf[8 + i].w * hv.w;
                a3 += wf[12 + i].x * hv.x + wf[12 + i].y * hv.y + wf[12 + i].z * hv.z + wf[12 + i].w * hv.w;
            }
            #pragma unroll
            for (int m = 1; m <= 16; m <<= 1) {
                a0 += __shfl_xor(a0, m); a1 += __shfl_xor(a1, m);
                a2 += __shfl_xor(a2, m); a3 += __shfl_xor(a3, m);
            }
            if (l == 0) {
                uint32_t* q = gfp + (size_t)s * G4H + growb;
                __hip_atomic_store(q + 0, f2u(a0 + xfc.x), __ATOMIC_RELAXED, __HIP_MEMORY_SCOPE_AGENT);
                __hip_atomic_store(q + 1, f2u(a1 + xfc.y), __ATOMIC_RELAXED, __HIP_MEMORY_SCOPE_AGENT);
                __hip_atomic_store(q + 2, f2u(a2 + xfc.z), __ATOMIC_RELAXED, __HIP_MEMORY_SCOPE_AGENT);
                __hip_atomic_store(q + 3, f2u(a3 + xfc.w), __ATOMIC_RELAXED, __HIP_MEMORY_SCOPE_AGENT);
                xff = make_float4(0.f, 0.f, 0.f, 0.f);
                if (s + 2 < TT)
                    xff = *(const float4*)(gxf + (size_t)(s + 2) * G4H + growb);
            }
        }

        // ================= backward half =================
        float hbv;
        if (s > 0) {
            const uint32_t* p = gbp + (size_t)(s - 1) * G4H + tid;
            uint32_t v0, v1, v2, v3;
            for (;;) {
                v0 = __hip_atomic_load(p,        __ATOMIC_RELAXED, __HIP_MEMORY_SCOPE_AGENT);
                v1 = __hip_atomic_load(p + 512,  __ATOMIC_RELAXED, __HIP_MEMORY_SCOPE_AGENT);
                v2 = __hip_atomic_load(p + 1024, __ATOMIC_RELAXED, __HIP_MEMORY_SCOPE_AGENT);
                v3 = __hip_atomic_load(p + 1536, __ATOMIC_RELAXED, __HIP_MEMORY_SCOPE_AGENT);
                if ((v0 != POISON) & (v1 != POISON) & (v2 != POISON) & (v3 != POISON)) break;
            }
            float gi = fsig(u2f(v0));
            float gf = fsig(u2f(v1));
            float gg = ftanh(u2f(v2));
            float go = fsig(u2f(v3));
            cb = gf * cb + gi * gg;
            hbv = go * ftanh(cb);
            if (wg == 0) hout[(size_t)(TT - s) * (2 * HH) + HH + tid] = hbv;
        } else {
            hbv = 0.f;
        }
        hb_s[tid] = hbv;
        __syncthreads();                               // B2: hb ready (also orders prev fwd dot)

        if (s < TT) {
            float a0 = 0.f, a1 = 0.f, a2 = 0.f, a3 = 0.f;
            const float4* h4 = (const float4*)hb_s;
            #pragma unroll
            for (int i = 0; i < 4; ++i) {
                float4 hv = h4[l + 32 * i];
                a0 += wb[0 + i].x * hv.x + wb[0 + i].y * hv.y + wb[0 + i].z * hv.z + wb[0 + i].w * hv.w;
                a1 += wb[4 + i].x * hv.x + wb[4 + i].y * hv.y + wb[4 + i].z * hv.z + wb[4 + i].w * hv.w;
                a2 += wb[8 + i].x * hv.x + wb[8 + i].y * hv.y + wb[8 + i].z * hv.z + wb[8 + i].w * hv.w;
                a3 += wb[12 + i].x * hv.x + wb[12 + i].y * hv.y + wb[12 + i].z * hv.z + wb[12 + i].w * hv.w;
            }
            #pragma unroll
            for (int m = 1; m <= 16; m <<= 1) {
                a0 += __shfl_xor(a0, m); a1 += __shfl_xor(a1, m);
                a2 += __shfl_xor(a2, m); a3 += __shfl_xor(a3, m);
            }
            if (l == 0) {
                uint32_t* q = gbp + (size_t)s * G4H + growb;
                __hip_atomic_store(q + 0, f2u(a0 + xbc.x), __ATOMIC_RELAXED, __HIP_MEMORY_SCOPE_AGENT);
                __hip_atomic_store(q + 1, f2u(a1 + xbc.y), __ATOMIC_RELAXED, __HIP_MEMORY_SCOPE_AGENT);
                __hip_atomic_store(q + 2, f2u(a2 + xbc.z), __ATOMIC_RELAXED, __HIP_MEMORY_SCOPE_AGENT);
                __hip_atomic_store(q + 3, f2u(a3 + xbc.w), __ATOMIC_RELAXED, __HIP_MEMORY_SCOPE_AGENT);
                xbf = make_float4(0.f, 0.f, 0.f, 0.f);
                if (s + 2 < TT)
                    xbf = *(const float4*)(gxb + (size_t)(TT - 3 - s) * G4H + growb);
            }
        }

        xfc = xfn; xfn = xff;
        xbc = xbn; xbn = xbf;
    }
}

// ---------------- Viterbi forward + backtrack (bp in LDS as bytes) -----------
__global__ void viterbi_kernel(const float* __restrict__ feats,
                               const float* __restrict__ trans,
                               int* __restrict__ out) {
    const int n = threadIdx.x;   // blockDim = 64 (one wave)
    __shared__ float fv_s[NTAG];
    __shared__ uint8_t bp_s[TT][NTAG];   // 51200 B
    float tr[NTAG];
    if (n < NTAG) {
        #pragma unroll
        for (int p = 0; p < NTAG; ++p) tr[p] = trans[n * NTAG + p];
    }
    float fv = (n == 0) ? 0.f : NEGV;
    for (int t = 0; t < TT; ++t) {
        if (n < NTAG) fv_s[n] = fv;
        __syncthreads();
        if (n < NTAG) {
            float best = -INFINITY; int bb = 0;
            #pragma unroll
            for (int p = 0; p < NTAG; ++p) {
                float sc = fv_s[p] + tr[p];
                if (sc > best) { best = sc; bb = p; }   // first-max tie rule
            }
            bp_s[t][n] = (uint8_t)bb;
            fv = best + feats[t * NTAG + n];
        }
        __syncthreads();
    }
    if (n < NTAG) fv_s[n] = fv;
    __syncthreads();
    if (n == 0) {
        float best = -INFINITY; int tag = 0;
        for (int p = 0; p < NTAG; ++p)
            if (fv_s[p] > best) { best = fv_s[p]; tag = p; }
        for (int t = TT - 1; t >= 0; --t) {
            out[t] = tag;
            tag = bp_s[t][tag];
        }
    }
}

extern "C" void kernel_launch(void* const* d_in, const int* in_sizes, int n_in,
                              void* d_out, int out_size, void* d_ws, size_t ws_size,
                              hipStream_t stream) {
    const int*   sent      = (const int*)d_in[0];
    const float* emb       = (const float*)d_in[1];
    const float* w_ih_l0_f = (const float*)d_in[2];
    const float* w_hh_l0_f = (const float*)d_in[3];
    const float* b_ih_l0_f = (const float*)d_in[4];
    const float* b_hh_l0_f = (const float*)d_in[5];
    const float* w_ih_l0_b = (const float*)d_in[6];
    const float* w_hh_l0_b = (const float*)d_in[7];
    const float* b_ih_l0_b = (const float*)d_in[8];
    const float* b_hh_l0_b = (const float*)d_in[9];
    const float* w_ih_l1_f = (const float*)d_in[10];
    const float* w_hh_l1_f = (const float*)d_in[11];
    const float* b_ih_l1_f = (const float*)d_in[12];
    const float* b_hh_l1_f = (const float*)d_in[13];
    const float* w_ih_l1_b = (const float*)d_in[14];
    const float* w_hh_l1_b = (const float*)d_in[15];
    const float* b_ih_l1_b = (const float*)d_in[16];
    const float* b_hh_l1_b = (const float*)d_in[17];
    const float* w_tag     = (const float*)d_in[18];
    const float* b_tag     = (const float*)d_in[19];
    const float* trans     = (const float*)d_in[20];

    char* ws = (char*)d_ws;
    float* x     = (float*)(ws);                 // T*300   = 2,457,600 B
    float* gx    = (float*)(ws + 2457600);       // 2*T*4H  = 33,554,432 B
    float* gates = (float*)(ws + 36012032);      // 2*T*4H  = 33,554,432 B
    float* h1    = (float*)(ws + 69566464);      // T*2H    = 8,388,608 B
    float* h2    = (float*)(ws + 77955072);      // T*2H    = 8,388,608 B
    float* feats = (float*)(ws + 86343680);      // T*25

    const int NGATES = 2 * TT * G4H;

    poison_kernel<<<2048, 256, 0, stream>>>((uint32_t*)gates, NGATES);

    embed_kernel<<<TT, 128, 0, stream>>>(sent, emb, x);

    dim3 g0(TT / BM, G4H / BN);
    gemm_abt<<<g0, 256, 0, stream>>>(x, EE, w_ih_l0_f, EE, b_ih_l0_f, b_hh_l0_f,
                                     gx, G4H, TT, G4H, EE);
    gemm_abt<<<g0, 256, 0, stream>>>(x, EE, w_ih_l0_b, EE, b_ih_l0_b, b_hh_l0_b,
                                     gx + (size_t)TT * G4H, G4H, TT, G4H, EE);
    lstm_kernel<<<32, 512, 0, stream>>>(gx, w_hh_l0_f, w_hh_l0_b, gates, h1);

    dim3 g1(TT / GM, G4H / GN);
    gemm128<<<g1, 256, 0, stream>>>(h1, 2 * HH, w_ih_l1_f, 2 * HH, b_ih_l1_f, b_hh_l1_f,
                                    gx, G4H, 2 * HH);
    gemm128<<<g1, 256, 0, stream>>>(h1, 2 * HH, w_ih_l1_b, 2 * HH, b_ih_l1_b, b_hh_l1_b,
                                    gx + (size_t)TT * G4H, G4H, 2 * HH);
    poison_kernel<<<2048, 256, 0, stream>>>((uint32_t*)gates, NGATES);
    lstm_kernel<<<32, 512, 0, stream>>>(gx, w_hh_l1_f, w_hh_l1_b, gates, h2);

    dim3 gf(TT / BM, 1);
    gemm_abt<<<gf, 256, 0, stream>>>(h2, 2 * HH, w_tag, 2 * HH, b_tag, nullptr,
                                     feats, NTAG, TT, NTAG, 2 * HH);

    viterbi_kernel<<<1, 64, 0, stream>>>(feats, trans, (int*)d_out);
}

// Round 5
// 11137.077 us; speedup vs baseline: 1.3559x; 1.3559x over previous
//
#include <hip/hip_runtime.h>
#include <cmath>

#define TT   2048
#define EE   300
#define HH   512
#define G4H  2048     // 4*H
#define NTAG 25
#define NEGV (-10000.0f)
#define POISON 0xFFBADBADu   // NaN payload; real gate values can never equal this

typedef uint32_t u32x4 __attribute__((ext_vector_type(4)));

__device__ __forceinline__ float fsig(float x)  { return 1.f / (1.f + __expf(-x)); }
__device__ __forceinline__ float ftanh(float x) { return 1.f - 2.f / (__expf(2.f * x) + 1.f); }
__device__ __forceinline__ uint32_t f2u(float x) { return __float_as_uint(x); }
__device__ __forceinline__ float u2f(uint32_t x) { return __uint_as_float(x); }

// 16B L2-bypassing load (coherent at L3 across XCDs): one round trip per poll
__device__ __forceinline__ u32x4 poll16(const uint32_t* p) {
    u32x4 v;
    asm volatile("global_load_dwordx4 %0, %1, off sc0 sc1\n\t"
                 "s_waitcnt vmcnt(0)"
                 : "=v"(v) : "v"(p) : "memory");
    return v;
}

// ---------------- poison gates buffer (data-as-sync sentinel) ----------------
__global__ void poison_kernel(uint32_t* __restrict__ p, int n) {
    int i = blockIdx.x * blockDim.x + threadIdx.x;
    for (; i < n; i += gridDim.x * blockDim.x) p[i] = POISON;
}

// ---------------- embedding gather ----------------
__global__ void embed_kernel(const int* __restrict__ sent,
                             const float* __restrict__ emb,
                             float* __restrict__ x) {
    int t = blockIdx.x;
    int row = sent[t];
    const float4* src = (const float4*)(emb + (size_t)row * EE);
    float4* dst = (float4*)(x + (size_t)t * EE);
    for (int i = threadIdx.x; i < EE / 4; i += blockDim.x) dst[i] = src[i];
}

// ---------------- GEMM (generic, bounds-checked): C = A*B^T + b1 (+ b2) ------
#define BM 64
#define BN 64
#define BKK 16
__global__ __launch_bounds__(256)
void gemm_abt(const float* __restrict__ A, int lda,
              const float* __restrict__ B, int ldb,
              const float* __restrict__ bias1,
              const float* __restrict__ bias2,
              float* __restrict__ C, int ldc,
              int M, int N, int K) {
    __shared__ float As[BKK][BM + 4];
    __shared__ float Bs[BKK][BN + 4];
    const int tid = threadIdx.x;
    const int tx = tid & 15, ty = tid >> 4;
    const int bm = blockIdx.x * BM, bn = blockIdx.y * BN;
    float acc[4][4] = {};
    for (int k0 = 0; k0 < K; k0 += BKK) {
        #pragma unroll
        for (int i = 0; i < 4; ++i) {
            int m = (tid >> 4) + i * 16;
            int k = tid & 15;
            float a = 0.f, b = 0.f;
            if (k0 + k < K) {
                if (bm + m < M) a = A[(size_t)(bm + m) * lda + k0 + k];
                if (bn + m < N) b = B[(size_t)(bn + m) * ldb + k0 + k];
            }
            As[k][m] = a;
            Bs[k][m] = b;
        }
        __syncthreads();
        #pragma unroll
        for (int k = 0; k < BKK; ++k) {
            float4 a4 = *(const float4*)&As[k][ty * 4];
            float4 b4 = *(const float4*)&Bs[k][tx * 4];
            acc[0][0] += a4.x * b4.x; acc[0][1] += a4.x * b4.y;
            acc[0][2] += a4.x * b4.z; acc[0][3] += a4.x * b4.w;
            acc[1][0] += a4.y * b4.x; acc[1][1] += a4.y * b4.y;
            acc[1][2] += a4.y * b4.z; acc[1][3] += a4.y * b4.w;
            acc[2][0] += a4.z * b4.x; acc[2][1] += a4.z * b4.y;
            acc[2][2] += a4.z * b4.z; acc[2][3] += a4.z * b4.w;
            acc[3][0] += a4.w * b4.x; acc[3][1] += a4.w * b4.y;
            acc[3][2] += a4.w * b4.z; acc[3][3] += a4.w * b4.w;
        }
        __syncthreads();
    }
    #pragma unroll
    for (int i = 0; i < 4; ++i) {
        int m = bm + ty * 4 + i;
        if (m < M) {
            #pragma unroll
            for (int j = 0; j < 4; ++j) {
                int n = bn + tx * 4 + j;
                if (n < N) {
                    float v = acc[i][j];
                    if (bias1) v += bias1[n];
                    if (bias2) v += bias2[n];
                    C[(size_t)m * ldc + n] = v;
                }
            }
        }
    }
}

// ---------------- big GEMM (128x128 tile, 8x8/thread) ----------------
#define GM 128
#define GN 128
#define GK 16
__global__ __launch_bounds__(256)
void gemm128(const float* __restrict__ A, int lda,
             const float* __restrict__ B, int ldb,
             const float* __restrict__ bias1,
             const float* __restrict__ bias2,
             float* __restrict__ C, int ldc, int K) {
    __shared__ float As[GK][GM + 4];
    __shared__ float Bs[GK][GN + 4];
    const int tid = threadIdx.x;
    const int tx = tid & 15, ty = tid >> 4;
    const int bm = blockIdx.x * GM, bn = blockIdx.y * GN;
    const int lm = tid >> 1, lkq = (tid & 1) * 8;
    float acc[8][8] = {};
    for (int k0 = 0; k0 < K; k0 += GK) {
        float4 a0 = *(const float4*)&A[(size_t)(bm + lm) * lda + k0 + lkq];
        float4 a1 = *(const float4*)&A[(size_t)(bm + lm) * lda + k0 + lkq + 4];
        float4 b0 = *(const float4*)&B[(size_t)(bn + lm) * ldb + k0 + lkq];
        float4 b1 = *(const float4*)&B[(size_t)(bn + lm) * ldb + k0 + lkq + 4];
        As[lkq + 0][lm] = a0.x; As[lkq + 1][lm] = a0.y;
        As[lkq + 2][lm] = a0.z; As[lkq + 3][lm] = a0.w;
        As[lkq + 4][lm] = a1.x; As[lkq + 5][lm] = a1.y;
        As[lkq + 6][lm] = a1.z; As[lkq + 7][lm] = a1.w;
        Bs[lkq + 0][lm] = b0.x; Bs[lkq + 1][lm] = b0.y;
        Bs[lkq + 2][lm] = b0.z; Bs[lkq + 3][lm] = b0.w;
        Bs[lkq + 4][lm] = b1.x; Bs[lkq + 5][lm] = b1.y;
        Bs[lkq + 6][lm] = b1.z; Bs[lkq + 7][lm] = b1.w;
        __syncthreads();
        #pragma unroll
        for (int k = 0; k < GK; ++k) {
            float4 x0 = *(const float4*)&As[k][ty * 8];
            float4 x1 = *(const float4*)&As[k][ty * 8 + 4];
            float4 y0 = *(const float4*)&Bs[k][tx * 8];
            float4 y1 = *(const float4*)&Bs[k][tx * 8 + 4];
            float xa[8] = {x0.x, x0.y, x0.z, x0.w, x1.x, x1.y, x1.z, x1.w};
            float yb[8] = {y0.x, y0.y, y0.z, y0.w, y1.x, y1.y, y1.z, y1.w};
            #pragma unroll
            for (int i = 0; i < 8; ++i)
                #pragma unroll
                for (int j = 0; j < 8; ++j)
                    acc[i][j] += xa[i] * yb[j];
        }
        __syncthreads();
    }
    #pragma unroll
    for (int i = 0; i < 8; ++i) {
        int m = bm + ty * 8 + i;
        float* cr = C + (size_t)m * ldc + bn + tx * 8;
        #pragma unroll
        for (int j = 0; j < 8; ++j) {
            float v = acc[i][j];
            int n = bn + tx * 8 + j;
            if (bias1) v += bias1[n];
            if (bias2) v += bias2[n];
            cr[j] = v;
        }
    }
}

// ------------- persistent BiLSTM recurrence (packed-gate publish) -------------
// 64 WGs x 512 threads: blockIdx<32 -> fwd, >=32 -> bwd (one dir per WG).
// Gates are packed [T][512][4] (i,f,g,o of unit u in one 16B quad), so the
// consumer polls ONE dwordx4 (one L3 round trip). Thread (g=tid>>5, l=tid&31)
// computes 4 consecutive rows of one gate block against h-chunk floats
// {4(l+32i)..+3, i=0..3} -> LDS traffic /4 vs r=1. Every WG redundantly tracks
// c[tid] (identical fp32 trajectory) -> no h broadcast needed.
__global__ __launch_bounds__(512, 1)
void lstm_kernel(const float* __restrict__ gx,      // [2][T][4H] input proj + biases (row-major gate blocks)
                 const float* __restrict__ whh_f,   // [4H][H]
                 const float* __restrict__ whh_b,   // [4H][H]
                 float* __restrict__ gates,         // [2][T][512][4] packed, poisoned
                 float* __restrict__ hout)          // [T][2H]
{
    const int tid = threadIdx.x;
    const int dir = blockIdx.x >> 5;
    const int wg  = blockIdx.x & 31;
    const int g   = tid >> 5;            // row group 0..15 (4 rows each)
    const int l   = tid & 31;            // reduction lane
    const int gb  = g >> 2;              // gate block (0=i 1=f 2=g 3=o)
    const int u0  = wg * 16 + (g & 3) * 4;       // first of 4 units
    const int growb = gb * HH + u0;              // first of 4 gate rows
    const float* W = dir ? whh_b : whh_f;

    // weights: 4 rows x 16 floats = 16 float4 per thread
    float4 w[16];
    #pragma unroll
    for (int j = 0; j < 4; ++j) {
        const float4* wr = (const float4*)(W + (size_t)(growb + j) * HH);
        #pragma unroll
        for (int i = 0; i < 4; ++i) w[j * 4 + i] = wr[l + 32 * i];
    }
    #pragma unroll
    for (int i = 0; i < 16; ++i)
        asm volatile("" : "+v"(w[i].x), "+v"(w[i].y), "+v"(w[i].z), "+v"(w[i].w));

    __shared__ float h_s[HH];

    float c = 0.f;                       // cell state of unit `tid` (replicated per WG)
    uint32_t* gpd = (uint32_t*)gates + (size_t)dir * TT * G4H;
    const float* gxd = gx + (size_t)dir * TT * G4H;

    // gx prefetch pipeline (l==0 lanes), one float4 = 4 consecutive rows
    float4 xc{}, xn{}, xf{};
    if (l == 0) {
        int t0 = dir ? TT - 1 : 0;
        int t1 = dir ? TT - 2 : 1;
        xc = *(const float4*)(gxd + (size_t)t0 * G4H + growb);
        xn = *(const float4*)(gxd + (size_t)t1 * G4H + growb);
    }

    for (int s = 0; s <= TT; ++s) {
        if (s > 0) {
            // poll the 4 packed gates of unit `tid` from step s-1: ONE dwordx4
            const uint32_t* p = gpd + ((size_t)(s - 1) * HH + tid) * 4;
            u32x4 v;
            for (;;) {
                v = poll16(p);
                if ((v.x != POISON) & (v.y != POISON) &
                    (v.z != POISON) & (v.w != POISON)) break;
            }
            float gi = fsig(u2f(v.x));
            float gf = fsig(u2f(v.y));
            float gg = ftanh(u2f(v.z));
            float go = fsig(u2f(v.w));
            c = gf * c + gi * gg;
            float h = go * ftanh(c);
            h_s[tid] = h;
            if (wg == 0) {
                int tp = dir ? (TT - s) : (s - 1);
                hout[(size_t)tp * (2 * HH) + dir * HH + tid] = h;
            }
        } else {
            h_s[tid] = 0.f;
        }
        __syncthreads();                             // B1: h_s ready
        if (s == TT) break;

        // prefetch gx for step s+2 (lands long before its use)
        if (l == 0) {
            xf = make_float4(0.f, 0.f, 0.f, 0.f);
            if (s + 2 < TT) {
                int tf = dir ? (TT - 3 - s) : (s + 2);
                xf = *(const float4*)(gxd + (size_t)tf * G4H + growb);
            }
        }

        // dot: 4 rows x h_prev, 16 floats/lane, 4 accumulators
        float a0 = 0.f, a1 = 0.f, a2 = 0.f, a3 = 0.f;
        const float4* h4 = (const float4*)h_s;
        #pragma unroll
        for (int i = 0; i < 4; ++i) {
            float4 hv = h4[l + 32 * i];
            a0 += w[0  + i].x * hv.x + w[0  + i].y * hv.y + w[0  + i].z * hv.z + w[0  + i].w * hv.w;
            a1 += w[4  + i].x * hv.x + w[4  + i].y * hv.y + w[4  + i].z * hv.z + w[4  + i].w * hv.w;
            a2 += w[8  + i].x * hv.x + w[8  + i].y * hv.y + w[8  + i].z * hv.z + w[8  + i].w * hv.w;
            a3 += w[12 + i].x * hv.x + w[12 + i].y * hv.y + w[12 + i].z * hv.z + w[12 + i].w * hv.w;
        }
        #pragma unroll
        for (int m = 1; m <= 16; m <<= 1) {
            a0 += __shfl_xor(a0, m); a1 += __shfl_xor(a1, m);
            a2 += __shfl_xor(a2, m); a3 += __shfl_xor(a3, m);
        }
        if (l == 0) {
            // 4 units' gate `gb`, stride 16B -> one 64B line (u0*16B is 64B-aligned)
            uint32_t* q = gpd + ((size_t)s * HH + u0) * 4 + gb;
            __hip_atomic_store(q + 0,  f2u(a0 + xc.x), __ATOMIC_RELAXED, __HIP_MEMORY_SCOPE_AGENT);
            __hip_atomic_store(q + 4,  f2u(a1 + xc.y), __ATOMIC_RELAXED, __HIP_MEMORY_SCOPE_AGENT);
            __hip_atomic_store(q + 8,  f2u(a2 + xc.z), __ATOMIC_RELAXED, __HIP_MEMORY_SCOPE_AGENT);
            __hip_atomic_store(q + 12, f2u(a3 + xc.w), __ATOMIC_RELAXED, __HIP_MEMORY_SCOPE_AGENT);
        }
        __syncthreads();                             // B2: h_s safe to overwrite
        xc = xn; xn = xf;
    }
}

// ---------------- Viterbi forward + backtrack (bp in LDS as bytes) -----------
__global__ void viterbi_kernel(const float* __restrict__ feats,
                               const float* __restrict__ trans,
                               int* __restrict__ out) {
    const int n = threadIdx.x;   // blockDim = 64 (one wave)
    __shared__ float fv_s[NTAG];
    __shared__ uint8_t bp_s[TT][NTAG];   // 51200 B
    float tr[NTAG];
    if (n < NTAG) {
        #pragma unroll
        for (int p = 0; p < NTAG; ++p) tr[p] = trans[n * NTAG + p];
    }
    float fv = (n == 0) ? 0.f : NEGV;
    for (int t = 0; t < TT; ++t) {
        if (n < NTAG) fv_s[n] = fv;
        __syncthreads();
        if (n < NTAG) {
            float best = -INFINITY; int bb = 0;
            #pragma unroll
            for (int p = 0; p < NTAG; ++p) {
                float sc = fv_s[p] + tr[p];
                if (sc > best) { best = sc; bb = p; }   // first-max tie rule
            }
            bp_s[t][n] = (uint8_t)bb;
            fv = best + feats[t * NTAG + n];
        }
        __syncthreads();
    }
    if (n < NTAG) fv_s[n] = fv;
    __syncthreads();
    if (n == 0) {
        float best = -INFINITY; int tag = 0;
        for (int p = 0; p < NTAG; ++p)
            if (fv_s[p] > best) { best = fv_s[p]; tag = p; }
        for (int t = TT - 1; t >= 0; --t) {
            out[t] = tag;
            tag = bp_s[t][tag];
        }
    }
}

extern "C" void kernel_launch(void* const* d_in, const int* in_sizes, int n_in,
                              void* d_out, int out_size, void* d_ws, size_t ws_size,
                              hipStream_t stream) {
    const int*   sent      = (const int*)d_in[0];
    const float* emb       = (const float*)d_in[1];
    const float* w_ih_l0_f = (const float*)d_in[2];
    const float* w_hh_l0_f = (const float*)d_in[3];
    const float* b_ih_l0_f = (const float*)d_in[4];
    const float* b_hh_l0_f = (const float*)d_in[5];
    const float* w_ih_l0_b = (const float*)d_in[6];
    const float* w_hh_l0_b = (const float*)d_in[7];
    const float* b_ih_l0_b = (const float*)d_in[8];
    const float* b_hh_l0_b = (const float*)d_in[9];
    const float* w_ih_l1_f = (const float*)d_in[10];
    const float* w_hh_l1_f = (const float*)d_in[11];
    const float* b_ih_l1_f = (const float*)d_in[12];
    const float* b_hh_l1_f = (const float*)d_in[13];
    const float* w_ih_l1_b = (const float*)d_in[14];
    const float* w_hh_l1_b = (const float*)d_in[15];
    const float* b_ih_l1_b = (const float*)d_in[16];
    const float* b_hh_l1_b = (const float*)d_in[17];
    const float* w_tag     = (const float*)d_in[18];
    const float* b_tag     = (const float*)d_in[19];
    const float* trans     = (const float*)d_in[20];

    char* ws = (char*)d_ws;
    float* x     = (float*)(ws);                 // T*300   = 2,457,600 B
    float* gx    = (float*)(ws + 2457600);       // 2*T*4H  = 33,554,432 B
    float* gates = (float*)(ws + 36012032);      // 2*T*4H  = 33,554,432 B (packed [T][512][4])
    float* h1    = (float*)(ws + 69566464);      // T*2H    = 8,388,608 B
    float* h2    = (float*)(ws + 77955072);      // T*2H    = 8,388,608 B
    float* feats = (float*)(ws + 86343680);      // T*25

    const int NGATES = 2 * TT * G4H;

    poison_kernel<<<2048, 256, 0, stream>>>((uint32_t*)gates, NGATES);

    embed_kernel<<<TT, 128, 0, stream>>>(sent, emb, x);

    dim3 g0(TT / BM, G4H / BN);
    gemm_abt<<<g0, 256, 0, stream>>>(x, EE, w_ih_l0_f, EE, b_ih_l0_f, b_hh_l0_f,
                                     gx, G4H, TT, G4H, EE);
    gemm_abt<<<g0, 256, 0, stream>>>(x, EE, w_ih_l0_b, EE, b_ih_l0_b, b_hh_l0_b,
                                     gx + (size_t)TT * G4H, G4H, TT, G4H, EE);
    lstm_kernel<<<64, 512, 0, stream>>>(gx, w_hh_l0_f, w_hh_l0_b, gates, h1);

    dim3 g1(TT / GM, G4H / GN);
    gemm128<<<g1, 256, 0, stream>>>(h1, 2 * HH, w_ih_l1_f, 2 * HH, b_ih_l1_f, b_hh_l1_f,
                                    gx, G4H, 2 * HH);
    gemm128<<<g1, 256, 0, stream>>>(h1, 2 * HH, w_ih_l1_b, 2 * HH, b_ih_l1_b, b_hh_l1_b,
                                    gx + (size_t)TT * G4H, G4H, 2 * HH);
    poison_kernel<<<2048, 256, 0, stream>>>((uint32_t*)gates, NGATES);
    lstm_kernel<<<64, 512, 0, stream>>>(gx, w_hh_l1_f, w_hh_l1_b, gates, h2);

    dim3 gf(TT / BM, 1);
    gemm_abt<<<gf, 256, 0, stream>>>(h2, 2 * HH, w_tag, 2 * HH, b_tag, nullptr,
                                     feats, NTAG, TT, NTAG, 2 * HH);

    viterbi_kernel<<<1, 64, 0, stream>>>(feats, trans, (int*)d_out);
}